// Round 3
// baseline (2872.735 us; speedup 1.0000x reference)
//
#include <hip/hip_runtime.h>
#include <math.h>

#define TH_ 80

__device__ __forceinline__ float silu_f(float x){ return x / (1.f + __expf(-x)); }
__device__ __forceinline__ float sigm_f(float x){ return 1.f / (1.f + __expf(-x)); }

__device__ __forceinline__ unsigned enc_f(float f){
  unsigned u = __float_as_uint(f);
  return (u & 0x80000000u) ? ~u : (u | 0x80000000u);
}
__device__ __forceinline__ float dec_f(unsigned u){
  return (u & 0x80000000u) ? __uint_as_float(u & 0x7fffffffu) : __uint_as_float(~u);
}

__device__ __forceinline__ void fma4(float4& a, float s, const float4 b){
  a.x += s*b.x; a.y += s*b.y; a.z += s*b.z; a.w += s*b.w;
}

__global__ void __launch_bounds__(256) k_init(unsigned* mx, float* den, float* agg, float* bn, int N){
  int t = blockIdx.x*256 + threadIdx.x;
  if (t < N*TH_) agg[t] = 0.f;
  if (t < N){ mx[t] = 0u; den[t] = 0.f; }
  if (t < 80) bn[t] = 0.f;
}

// 8 edges / 256-thread block. Slot = (tp-row r, col-quad). Each W2 element is
// loaded by exactly ONE lane (1 KB unique contiguous per wave instruction);
// u[e,h] comes from LDS broadcast. Thread accumulates t_e[r, colquad] for all
// 8 edges in registers over the h-contraction, then applies per-edge
// geometric coefficients and LDS-atomic-reduces into the message accumulator.
__global__ void __launch_bounds__(256) k_edge(
    const float* __restrict__ nf, const int* __restrict__ ei,
    const float* __restrict__ sh, const float* __restrict__ radial,
    const float* __restrict__ env,
    const float* __restrict__ W1, const float* __restrict__ b1,
    const float* __restrict__ W2, const float* __restrict__ b2,
    const float* __restrict__ Wq, const float* __restrict__ bq,
    const float* __restrict__ Wk, const float* __restrict__ bk,
    float* __restrict__ msgs, float* __restrict__ logits,
    unsigned* __restrict__ mx, int E)
{
  __shared__ float u_t[64][8];     // u transposed [h][e] -> broadcast reads
  __shared__ float feat[8][80];
  __shared__ float cAB[8][48];     // scalar-path coefficients (a0 folded)
  __shared__ float cV[8][64][3];   // vector-path coefficients (a1 folded)
  __shared__ float macc[8][80];
  __shared__ float shl[8][4];
  __shared__ float radl[8][16];
  __shared__ int   src_l[8], dst_l[8];

  const int t = threadIdx.x;
  const int e0 = blockIdx.x*8;

  // ---- stage 1: indices, sh, radial; zero macc
  if (t < 8){
    int ee = e0 + t; int ec = (ee < E) ? ee : (E-1);
    src_l[t] = ei[ec]; dst_l[t] = ei[E + ec];
  }
  if (t >= 64 && t < 96){
    int i = t - 64; int e = i >> 2, c = i & 3;
    int ee = e0 + e; int ec = (ee < E) ? ee : (E-1);
    shl[e][c] = sh[(size_t)ec*4 + c];
  }
  if (t >= 128 && t < 256){
    int i = t - 128; int e = i >> 4, r = i & 15;
    int ee = e0 + e; int ec = (ee < E) ? ee : (E-1);
    radl[e][r] = radial[(size_t)ec*16 + r];
  }
  for (int i = t; i < 640; i += 256) ((float*)macc)[i] = 0.f;
  __syncthreads();

  // ---- stage 2: src features + u = silu(radial@W1+b1) (transposed store)
  for (int i = t; i < 640; i += 256){
    int e = i / 80, idx = i - e*80;
    feat[e][idx] = nf[(size_t)src_l[e]*80 + idx];
  }
  {
    int e = t >> 5, hb = (t & 31)*2;
    #pragma unroll
    for (int hh = 0; hh < 2; ++hh){
      int h = hb + hh;
      float acc = b1[h];
      #pragma unroll
      for (int r = 0; r < 16; ++r) acc += radl[e][r]*W1[r*64+h];
      u_t[h][e] = silu_f(acc);
    }
  }
  __syncthreads();

  const float inv_s3 = 0.57735026918962576f;
  const float inv_s2 = 0.70710678118654752f;
  const float a0 = 0.14433756729740643f;  // 1/sqrt(48)
  const float a1 = 0.125f;                // 1/sqrt(64)

  // ---- stage 3: coefficients
  for (int i = t; i < 384; i += 256){
    int e = i / 48, r = i - e*48;
    float val;
    if (r < 32) val = a0 * shl[e][0] * feat[e][r];
    else {
      int v = r - 32;
      float dot = (feat[e][32+v*3+0]*shl[e][1] + feat[e][32+v*3+1]*shl[e][2]
                 + feat[e][32+v*3+2]*shl[e][3]) * inv_s3;
      val = a0 * dot;
    }
    cAB[e][r] = val;
  }
  for (int i = t; i < 1536; i += 256){
    int e = i / 192, j = i - e*192, r = j / 3, c = j - (j/3)*3;
    float val;
    if (r < 32) val = a1 * shl[e][1+c] * feat[e][r];
    else if (r < 48){
      int v = r - 32;
      val = a1 * shl[e][0] * feat[e][32+v*3+c];
    } else {
      int v = r - 48;
      int c1 = (c+1)%3, c2 = (c+2)%3;
      float cr = (feat[e][32+v*3+c1]*shl[e][1+c2] - feat[e][32+v*3+c2]*shl[e][1+c1]) * inv_s2;
      val = a1 * cr;
    }
    cV[e][r][c] = val;
  }
  __syncthreads();

  // ---- slot setup
  // slot A (all threads): scalar slots 0..255  : rA = t>>3 (WA rows), kqA = t&7
  const int rA = t >> 3, kqA = t & 7;
  const int rowA = (rA < 32) ? rA*32 : 1024 + (rA-32)*32;
  const float* pA = W2 + rowA + kqA*4;
  const float4 bA = *(const float4*)(b2 + rowA + kqA*4);
  // slot B: t<128 -> scalar slots 256..383 (WB rows); t>=128 -> vector slots 0..127 (WC rows)
  const bool Bscal = (t < 128);
  int rB, kqB, rowB;
  if (Bscal){ int s = 256 + t; rB = s >> 3; kqB = s & 7; rowB = 1024 + (rB-32)*32; }
  else { int v = t - 128; rB = v >> 2; kqB = v & 3; rowB = 1536 + rB*16; }
  const float* pB = W2 + rowB + kqB*4;
  const float4 bB = *(const float4*)(b2 + rowB + kqB*4);
  // slot C (t<128 only): vector slots 128..255 (WD/WE rows)
  const bool hasC = (t < 128);
  const int rC = 32 + (t >> 2), kqC = t & 3;
  const int rowC = (rC < 48) ? 2048 + (rC-32)*16 : 2304 + (rC-48)*16;
  const float* pC = W2 + rowC + kqC*4;
  const float4 bC = *(const float4*)(b2 + rowC + kqC*4);

  float4 accA[8], accB[8], accC[8];
  #pragma unroll
  for (int e = 0; e < 8; ++e){ accA[e] = bA; accB[e] = bB; accC[e] = bC; }

  // ---- main h-contraction: t_e[r,colquad] = b2 + sum_h u[e,h]*W2[h,r,colquad]
  #pragma unroll 2
  for (int h = 0; h < 64; ++h){
    const float4 u01 = *(const float4*)&u_t[h][0];
    const float4 u23 = *(const float4*)&u_t[h][4];
    const float4 wA = *(const float4*)(pA + (size_t)h*2560);
    fma4(accA[0], u01.x, wA); fma4(accA[1], u01.y, wA);
    fma4(accA[2], u01.z, wA); fma4(accA[3], u01.w, wA);
    fma4(accA[4], u23.x, wA); fma4(accA[5], u23.y, wA);
    fma4(accA[6], u23.z, wA); fma4(accA[7], u23.w, wA);
    const float4 wB = *(const float4*)(pB + (size_t)h*2560);
    fma4(accB[0], u01.x, wB); fma4(accB[1], u01.y, wB);
    fma4(accB[2], u01.z, wB); fma4(accB[3], u01.w, wB);
    fma4(accB[4], u23.x, wB); fma4(accB[5], u23.y, wB);
    fma4(accB[6], u23.z, wB); fma4(accB[7], u23.w, wB);
    if (hasC){
      const float4 wC = *(const float4*)(pC + (size_t)h*2560);
      fma4(accC[0], u01.x, wC); fma4(accC[1], u01.y, wC);
      fma4(accC[2], u01.z, wC); fma4(accC[3], u01.w, wC);
      fma4(accC[4], u23.x, wC); fma4(accC[5], u23.y, wC);
      fma4(accC[6], u23.z, wC); fma4(accC[7], u23.w, wC);
    }
  }

  // ---- epilogue: apply coefficients, reduce into macc
  #pragma unroll
  for (int e = 0; e < 8; ++e){
    float c = cAB[e][rA];
    atomicAdd(&macc[e][kqA*4+0], c*accA[e].x);
    atomicAdd(&macc[e][kqA*4+1], c*accA[e].y);
    atomicAdd(&macc[e][kqA*4+2], c*accA[e].z);
    atomicAdd(&macc[e][kqA*4+3], c*accA[e].w);
  }
  if (Bscal){
    #pragma unroll
    for (int e = 0; e < 8; ++e){
      float c = cAB[e][rB];
      atomicAdd(&macc[e][kqB*4+0], c*accB[e].x);
      atomicAdd(&macc[e][kqB*4+1], c*accB[e].y);
      atomicAdd(&macc[e][kqB*4+2], c*accB[e].z);
      atomicAdd(&macc[e][kqB*4+3], c*accB[e].w);
    }
  } else {
    #pragma unroll
    for (int e = 0; e < 8; ++e){
      float c0 = cV[e][rB][0], c1 = cV[e][rB][1], c2 = cV[e][rB][2];
      float a[4] = {accB[e].x, accB[e].y, accB[e].z, accB[e].w};
      #pragma unroll
      for (int i = 0; i < 4; ++i){
        int base = 32 + (kqB*4+i)*3;
        atomicAdd(&macc[e][base+0], c0*a[i]);
        atomicAdd(&macc[e][base+1], c1*a[i]);
        atomicAdd(&macc[e][base+2], c2*a[i]);
      }
    }
  }
  if (hasC){
    #pragma unroll
    for (int e = 0; e < 8; ++e){
      float c0 = cV[e][rC][0], c1 = cV[e][rC][1], c2 = cV[e][rC][2];
      float a[4] = {accC[e].x, accC[e].y, accC[e].z, accC[e].w};
      #pragma unroll
      for (int i = 0; i < 4; ++i){
        int base = 32 + (kqC*4+i)*3;
        atomicAdd(&macc[e][base+0], c0*a[i]);
        atomicAdd(&macc[e][base+1], c1*a[i]);
        atomicAdd(&macc[e][base+2], c2*a[i]);
      }
    }
  }
  __syncthreads();

  // ---- logits (wave 0): q.k attention with shuffle reduce over kq
  if (t < 64){
    const int l = t;
    const int e = l >> 3;
    const int kq = l & 7;
    const int eg = e0 + e;
    const bool act = (eg < E);
    float4 ms = *(const float4*)&macc[e][kq*4];
    int dn = dst_l[e];
    float4 qs = *(const float4*)(nf + (size_t)dn*80 + kq*4);
    float pk[8], pq[8];
    #pragma unroll
    for (int j = 0; j < 8; ++j){
      pk[j] = ms.x*Wk[(kq*4+0)*8+j] + ms.y*Wk[(kq*4+1)*8+j]
            + ms.z*Wk[(kq*4+2)*8+j] + ms.w*Wk[(kq*4+3)*8+j];
      pq[j] = qs.x*Wq[(kq*4+0)*8+j] + qs.y*Wq[(kq*4+1)*8+j]
            + qs.z*Wq[(kq*4+2)*8+j] + qs.w*Wq[(kq*4+3)*8+j];
    }
    #pragma unroll
    for (int m = 1; m < 8; m <<= 1){
      #pragma unroll
      for (int j = 0; j < 8; ++j){
        pk[j] += __shfl_xor(pk[j], m);
        pq[j] += __shfl_xor(pq[j], m);
      }
    }
    if (kq == 0 && act){
      float lg = 0.f;
      #pragma unroll
      for (int j = 0; j < 8; ++j) lg += (pq[j]+bq[j])*(pk[j]+bk[j]);
      lg *= 0.35355339059327373f;  // 1/sqrt(8)
      lg += logf(env[eg] + 1e-8f);
      logits[eg] = lg;
      atomicMax(&mx[dn], enc_f(lg));
    }
  }

  // ---- store messages
  for (int i = t; i < 160; i += 256){
    int e = i/20, r = i - (i/20)*20;
    if (e0 + e < E)
      ((float4*)(msgs + (size_t)(e0+e)*80))[r] = *(const float4*)&macc[e][r*4];
  }
}

__global__ void __launch_bounds__(256) k_soft1(const float* __restrict__ logits,
    const int* __restrict__ ei, const unsigned* __restrict__ mx,
    float* __restrict__ den, float* __restrict__ exb, int E){
  int e = blockIdx.x*256 + threadIdx.x;
  if (e >= E) return;
  int d = ei[E + e];
  float ex = __expf(logits[e] - dec_f(mx[d]));
  exb[e] = ex;
  atomicAdd(&den[d], ex);
}

__global__ void __launch_bounds__(256) k_scatter(const float* __restrict__ msgs,
    const float* __restrict__ exb, const float* __restrict__ den,
    const int* __restrict__ ei, float* __restrict__ agg, int E){
  int t = blockIdx.x*256 + threadIdx.x;
  if (t >= E*20) return;
  int e = t/20, r = t - (t/20)*20;
  int d = ei[E + e];
  float attn = exb[e] / (den[d] + 1e-8f);
  float4 m4 = ((const float4*)(msgs + (size_t)e*80))[r];
  float* ap = agg + (size_t)d*80 + r*4;
  atomicAdd(ap+0, attn*m4.x);
  atomicAdd(ap+1, attn*m4.y);
  atomicAdd(ap+2, attn*m4.z);
  atomicAdd(ap+3, attn*m4.w);
}

__global__ void __launch_bounds__(256) k_node(const float* __restrict__ agg,
    const float* __restrict__ nf,
    const float* __restrict__ Wout_s, const float* __restrict__ Wout_v,
    const float* __restrict__ Wg_s, const float* __restrict__ Wg_v,
    float* __restrict__ xbuf, float* __restrict__ bnacc, int N)
{
  __shared__ float t1[4][96];
  __shared__ float t2[4][96];
  __shared__ float bnl[80];
  int t = threadIdx.x, l = t & 63, wv = t >> 6;
  int n = blockIdx.x*4 + wv;
  bool act = (n < N);
  int nc = act ? n : 0;
  if (t < 80) bnl[t] = 0.f;
  __syncthreads();
  const float* arow = agg + (size_t)nc*80;
  const float iS = 0.17677669529663687f;  // 1/sqrt(32)
  const float iV = 0.25f;                 // 1/sqrt(16)
  for (int o = l; o < 80; o += 64){
    float val = 0.f;
    if (o < 32){
      for (int s = 0; s < 32; ++s) val += arow[s]*Wout_s[s*32+o];
      val *= iS;
    } else {
      int w = (o-32)/3, c = (o-32)-w*3;
      for (int v = 0; v < 16; ++v) val += arow[32+v*3+c]*Wout_v[v*16+w];
      val *= iV;
    }
    t1[wv][o] = val;
  }
  __syncthreads();
  for (int o = l; o < 96; o += 64){
    float val = 0.f;
    if (o < 48){
      for (int k = 0; k < 32; ++k) val += t1[wv][k]*Wg_s[k*48+o];
      val *= iS;
    } else {
      int w = (o-48)/3, c = (o-48)-w*3;
      for (int v = 0; v < 16; ++v) val += t1[wv][32+v*3+c]*Wg_v[v*16+w];
      val *= iV;
    }
    t2[wv][o] = val;
  }
  __syncthreads();
  for (int o = l; o < 80; o += 64){
    float x;
    if (o < 32){
      x = silu_f(t2[wv][o]) + nf[(size_t)nc*80+o];
      if (act){
        xbuf[(size_t)n*80+o] = x;
        atomicAdd(&bnl[o], x);
        atomicAdd(&bnl[32+o], x*x);
      }
    } else {
      int w = (o-32)/3;
      x = sigm_f(t2[wv][32+w]) * t2[wv][48+(o-32)] + nf[(size_t)nc*80+o];
      if (act){
        xbuf[(size_t)n*80+o] = x;
        atomicAdd(&bnl[64+w], x*x);
      }
    }
  }
  __syncthreads();
  if (t < 80) atomicAdd(&bnacc[t], bnl[t]);
}

__global__ void k_bn(const float* __restrict__ bnacc,
    const float* __restrict__ bn_ws, const float* __restrict__ bn_bs,
    const float* __restrict__ bn_wv, float* __restrict__ coef, int N){
  int t = threadIdx.x;
  float fN = (float)N;
  if (t < 32){
    float mean = bnacc[t]/fN;
    float var = bnacc[32+t]/fN - mean*mean;
    float cm = bn_ws[t]*rsqrtf(var + 1e-5f);
    coef[t] = cm;
    coef[32+t] = bn_bs[t] - mean*cm;
  } else if (t < 48){
    int v = t - 32;
    float vn = bnacc[64+v]/(3.f*fN);
    coef[64+v] = bn_wv[v]*rsqrtf(vn + 1e-5f);
  }
}

__global__ void __launch_bounds__(256) k_out(const float* __restrict__ xbuf,
    const float* __restrict__ coef, float* __restrict__ out, int N){
  int t = blockIdx.x*256 + threadIdx.x;
  if (t >= N*80) return;
  int n = t/80, o = t - n*80;
  float x = xbuf[t];
  out[t] = (o < 32) ? (x*coef[o] + coef[32+o]) : (x*coef[64+(o-32)/3]);
}

extern "C" void kernel_launch(void* const* d_in, const int* in_sizes, int n_in,
                              void* d_out, int out_size, void* d_ws, size_t ws_size,
                              hipStream_t stream) {
  const float* nf     = (const float*)d_in[0];
  const int*   ei     = (const int*)  d_in[1];
  const float* sh     = (const float*)d_in[2];
  const float* radial = (const float*)d_in[3];
  const float* env    = (const float*)d_in[4];
  const float* W1     = (const float*)d_in[5];
  const float* b1     = (const float*)d_in[6];
  const float* W2     = (const float*)d_in[7];
  const float* b2     = (const float*)d_in[8];
  const float* Wq     = (const float*)d_in[9];
  const float* bq     = (const float*)d_in[10];
  const float* Wk     = (const float*)d_in[11];
  const float* bk     = (const float*)d_in[12];
  const float* Wout_s = (const float*)d_in[13];
  const float* Wout_v = (const float*)d_in[14];
  const float* Wg_s   = (const float*)d_in[15];
  const float* Wg_v   = (const float*)d_in[16];
  const float* bn_ws  = (const float*)d_in[17];
  const float* bn_bs  = (const float*)d_in[18];
  const float* bn_wv  = (const float*)d_in[19];

  const int E = in_sizes[4];
  const int N = in_sizes[0] / 80;

  float* ws = (float*)d_ws;
  size_t off = 0;
  float* msgs   = ws + off; off += (size_t)E*80;
  float* logits = ws + off; off += E;
  float* exb    = ws + off; off += E;
  unsigned* mx  = (unsigned*)(ws + off); off += N;
  float* den    = ws + off; off += N;
  float* agg    = ws + off; off += (size_t)N*80;
  float* xbuf   = ws + off; off += (size_t)N*80;
  float* bnacc  = ws + off; off += 80;
  float* coef   = ws + off; off += 80;

  k_init<<<(N*80 + 255)/256, 256, 0, stream>>>(mx, den, agg, bnacc, N);
  k_edge<<<(E + 7)/8, 256, 0, stream>>>(nf, ei, sh, radial, env,
      W1, b1, W2, b2, Wq, bq, Wk, bk, msgs, logits, mx, E);
  k_soft1<<<(E + 255)/256, 256, 0, stream>>>(logits, ei, mx, den, exb, E);
  k_scatter<<<(E*20 + 255)/256, 256, 0, stream>>>(msgs, exb, den, ei, agg, E);
  k_node<<<(N + 3)/4, 256, 0, stream>>>(agg, nf, Wout_s, Wout_v, Wg_s, Wg_v, xbuf, bnacc, N);
  k_bn<<<1, 64, 0, stream>>>(bnacc, bn_ws, bn_bs, bn_wv, coef, N);
  k_out<<<(N*80 + 255)/256, 256, 0, stream>>>(xbuf, coef, (float*)d_out, N);
}

// Round 4
// 658.941 us; speedup vs baseline: 4.3596x; 4.3596x over previous
//
#include <hip/hip_runtime.h>
#include <math.h>

#define TH_ 80

typedef __bf16 bf16x8 __attribute__((ext_vector_type(8)));
typedef float  f32x4  __attribute__((ext_vector_type(4)));

__device__ __forceinline__ float silu_f(float x){ return x / (1.f + __expf(-x)); }
__device__ __forceinline__ float sigm_f(float x){ return 1.f / (1.f + __expf(-x)); }

__device__ __forceinline__ unsigned enc_f(float f){
  unsigned u = __float_as_uint(f);
  return (u & 0x80000000u) ? ~u : (u | 0x80000000u);
}
__device__ __forceinline__ float dec_f(unsigned u){
  return (u & 0x80000000u) ? __uint_as_float(u & 0x7fffffffu) : __uint_as_float(~u);
}

__global__ void __launch_bounds__(256) k_init(unsigned* mx, float* den, float* agg, float* bn, int N){
  int t = blockIdx.x*256 + threadIdx.x;
  if (t < N*TH_) agg[t] = 0.f;
  if (t < N){ mx[t] = 0u; den[t] = 0.f; }
  if (t < 80) bn[t] = 0.f;
}

// W2 (fp32 [64][2560]) -> W2t (bf16, [kc][2560][32]), kc = h>>5, h' = h&31
__global__ void __launch_bounds__(256) k_prep(const float* __restrict__ W2, __bf16* __restrict__ W2t){
  int gid = blockIdx.x*256 + threadIdx.x;   // 163840 total, read-coalesced
  int h = gid >> 11;         // gid / 2048? no: 2560 cols -- use div
  h = gid / 2560;
  int col = gid - h*2560;
  int kc = h >> 5, hp = h & 31;
  W2t[(size_t)kc*81920 + col*32 + hp] = (__bf16)W2[gid];
}

// 16 edges / 256-thread block, bf16 MFMA over the h-contraction.
// A = u[16x64] bf16 (LDS), B = W2t tiles (global, L2-resident).
// Fused epilogue: per-lane coefficient multiply into 20 msg partials,
// cross-wave reduce via LDS atomics; b2 folded into macc init.
__global__ void __launch_bounds__(256) k_edge(
    const float* __restrict__ nf, const int* __restrict__ ei,
    const float* __restrict__ sh, const float* __restrict__ radial,
    const float* __restrict__ env,
    const float* __restrict__ W1, const float* __restrict__ b1,
    const __bf16* __restrict__ W2t, const float* __restrict__ b2,
    const float* __restrict__ Wq, const float* __restrict__ bq,
    const float* __restrict__ Wk, const float* __restrict__ bk,
    float* __restrict__ msgs, float* __restrict__ logits,
    unsigned* __restrict__ mx, int E)
{
  __shared__ __bf16 u_lds[16][72];   // pad 72: 16B-aligned rows
  __shared__ float feat[16][80];
  __shared__ float cAB[16][48];
  __shared__ float cV[16][64][3];
  __shared__ float macc[16][80];
  __shared__ float shl[16][4];
  __shared__ float radl[16][16];
  __shared__ int   src_l[16], dst_l[16];

  const int t = threadIdx.x;
  const int e0 = blockIdx.x*16;

  // ---- stage 1: indices, sh, radial
  if (t < 16){
    int ee = e0 + t; int ec = (ee < E) ? ee : (E-1);
    src_l[t] = ei[ec]; dst_l[t] = ei[E + ec];
  }
  if (t >= 64 && t < 128){
    int i = t - 64; int e = i >> 2, c = i & 3;
    int ee = e0 + e; int ec = (ee < E) ? ee : (E-1);
    shl[e][c] = sh[(size_t)ec*4 + c];
  }
  {
    int e = t >> 4, r = t & 15;
    int ee = e0 + e; int ec = (ee < E) ? ee : (E-1);
    radl[e][r] = radial[(size_t)ec*16 + r];
  }
  __syncthreads();

  // ---- stage 2: src features + u = silu(radial@W1+b1) -> bf16 LDS
  for (int i = t; i < 1280; i += 256){
    int e = i / 80, idx = i - e*80;
    feat[e][idx] = nf[(size_t)src_l[e]*80 + idx];
  }
  for (int i = t; i < 1024; i += 256){
    int e = i & 15, h = i >> 4;
    float acc = b1[h];
    #pragma unroll
    for (int r = 0; r < 16; ++r) acc += radl[e][r]*W1[r*64+h];
    u_lds[e][h] = (__bf16)silu_f(acc);
  }
  __syncthreads();

  const float inv_s3 = 0.57735026918962576f;
  const float inv_s2 = 0.70710678118654752f;
  const float a0 = 0.14433756729740643f;  // 1/sqrt(48)
  const float a1 = 0.125f;                // 1/sqrt(64)

  // ---- stage 3: coefficients
  for (int i = t; i < 768; i += 256){
    int e = i / 48, r = i - (i/48)*48;
    float val;
    if (r < 32) val = a0 * shl[e][0] * feat[e][r];
    else {
      int v = r - 32;
      float dot = (feat[e][32+v*3+0]*shl[e][1] + feat[e][32+v*3+1]*shl[e][2]
                 + feat[e][32+v*3+2]*shl[e][3]) * inv_s3;
      val = a0 * dot;
    }
    cAB[e][r] = val;
  }
  for (int i = t; i < 3072; i += 256){
    int e = i / 192, j = i - (i/192)*192, r = j / 3, c = j - (j/3)*3;
    float val;
    if (r < 32) val = a1 * shl[e][1+c] * feat[e][r];
    else if (r < 48){
      int v = r - 32;
      val = a1 * shl[e][0] * feat[e][32+v*3+c];
    } else {
      int v = r - 48;
      int c1 = (c+1)%3, c2 = (c+2)%3;
      float cr = (feat[e][32+v*3+c1]*shl[e][1+c2] - feat[e][32+v*3+c2]*shl[e][1+c1]) * inv_s2;
      val = a1 * cr;
    }
    cV[e][r][c] = val;
  }
  __syncthreads();

  // ---- stage 4: macc init = coefficient-contracted b2 (bias fold)
  for (int i = t; i < 512; i += 256){
    int e = i >> 5, k = i & 31;
    float val = 0.f;
    #pragma unroll 4
    for (int r = 0; r < 48; ++r) val += cAB[e][r]*b2[r*32+k];
    macc[e][k] = val;
  }
  for (int i = t; i < 768; i += 256){
    int e = i / 48, rem = i - (i/48)*48, k = rem/3, c = rem - (rem/3)*3;
    float val = 0.f;
    #pragma unroll 4
    for (int r = 0; r < 64; ++r) val += cV[e][r][c]*b2[1536+r*16+k];
    macc[e][32+k*3+c] = val;
  }
  __syncthreads();

  // ---- stage 5: MFMA tile loop (40 col-tiles per wave)
  const int lane = t & 63;
  const int wv   = t >> 6;
  const int quad = lane >> 4;
  const int nlo  = lane & 15;

  bf16x8 afr0 = *(const bf16x8*)&u_lds[nlo][quad*8];        // kc=0
  bf16x8 afr1 = *(const bf16x8*)&u_lds[nlo][32 + quad*8];   // kc=1

  float accS0[4] = {0,0,0,0};   // k_out = nlo
  float accS1[4] = {0,0,0,0};   // k_out = 16+nlo
  float accV0[4] = {0,0,0,0};   // c=0, k=nlo
  float accV1[4] = {0,0,0,0};
  float accV2[4] = {0,0,0,0};

  for (int it = wv*40; it < wv*40 + 40; ++it){
    const int n0 = it*16;
    const __bf16* bp = W2t + (size_t)(n0 + nlo)*32 + quad*8;
    bf16x8 bf0 = *(const bf16x8*)(bp);
    bf16x8 bf1 = *(const bf16x8*)(bp + 81920);
    f32x4 d = {0.f,0.f,0.f,0.f};
    d = __builtin_amdgcn_mfma_f32_16x16x32_bf16(afr0, bf0, d, 0, 0, 0);
    d = __builtin_amdgcn_mfma_f32_16x16x32_bf16(afr1, bf1, d, 0, 0, 0);
    if (n0 < 1536){
      const int r = n0 >> 5;
      if (((n0 >> 4) & 1) == 0){
        #pragma unroll
        for (int reg = 0; reg < 4; ++reg)
          accS0[reg] += cAB[quad*4+reg][r]*d[reg];
      } else {
        #pragma unroll
        for (int reg = 0; reg < 4; ++reg)
          accS1[reg] += cAB[quad*4+reg][r]*d[reg];
      }
    } else {
      const int r = (n0 - 1536) >> 4;
      #pragma unroll
      for (int reg = 0; reg < 4; ++reg){
        const int m = quad*4+reg;
        const float dd = d[reg];
        accV0[reg] += cV[m][r][0]*dd;
        accV1[reg] += cV[m][r][1]*dd;
        accV2[reg] += cV[m][r][2]*dd;
      }
    }
  }

  // ---- cross-wave/lane reduce into macc
  #pragma unroll
  for (int reg = 0; reg < 4; ++reg){
    const int m = quad*4+reg;
    atomicAdd(&macc[m][nlo],        accS0[reg]);
    atomicAdd(&macc[m][16+nlo],     accS1[reg]);
    atomicAdd(&macc[m][32+nlo*3+0], accV0[reg]);
    atomicAdd(&macc[m][32+nlo*3+1], accV1[reg]);
    atomicAdd(&macc[m][32+nlo*3+2], accV2[reg]);
  }
  __syncthreads();

  // ---- logits (waves 0-1: 8 edges each)
  if (t < 128){
    const int l = t & 63;
    const int e = (t >> 6)*8 + (l >> 3);
    const int kq = l & 7;
    const int eg = e0 + e;
    const bool act = (eg < E);
    float4 ms = *(const float4*)&macc[e][kq*4];
    int dn = dst_l[e];
    float4 qs = *(const float4*)(nf + (size_t)dn*80 + kq*4);
    float pk[8], pq[8];
    #pragma unroll
    for (int j = 0; j < 8; ++j){
      pk[j] = ms.x*Wk[(kq*4+0)*8+j] + ms.y*Wk[(kq*4+1)*8+j]
            + ms.z*Wk[(kq*4+2)*8+j] + ms.w*Wk[(kq*4+3)*8+j];
      pq[j] = qs.x*Wq[(kq*4+0)*8+j] + qs.y*Wq[(kq*4+1)*8+j]
            + qs.z*Wq[(kq*4+2)*8+j] + qs.w*Wq[(kq*4+3)*8+j];
    }
    #pragma unroll
    for (int m = 1; m < 8; m <<= 1){
      #pragma unroll
      for (int j = 0; j < 8; ++j){
        pk[j] += __shfl_xor(pk[j], m);
        pq[j] += __shfl_xor(pq[j], m);
      }
    }
    if (kq == 0 && act){
      float lg = 0.f;
      #pragma unroll
      for (int j = 0; j < 8; ++j) lg += (pq[j]+bq[j])*(pk[j]+bk[j]);
      lg *= 0.35355339059327373f;  // 1/sqrt(8)
      lg += logf(env[eg] + 1e-8f);
      logits[eg] = lg;
      atomicMax(&mx[dn], enc_f(lg));
    }
  }

  // ---- store messages
  for (int i = t; i < 320; i += 256){
    int e = i/20, r = i - (i/20)*20;
    if (e0 + e < E)
      ((float4*)(msgs + (size_t)(e0+e)*80))[r] = *(const float4*)&macc[e][r*4];
  }
}

__global__ void __launch_bounds__(256) k_soft1(const float* __restrict__ logits,
    const int* __restrict__ ei, const unsigned* __restrict__ mx,
    float* __restrict__ den, float* __restrict__ exb, int E){
  int e = blockIdx.x*256 + threadIdx.x;
  if (e >= E) return;
  int d = ei[E + e];
  float ex = __expf(logits[e] - dec_f(mx[d]));
  exb[e] = ex;
  atomicAdd(&den[d], ex);
}

__global__ void __launch_bounds__(256) k_scatter(const float* __restrict__ msgs,
    const float* __restrict__ exb, const float* __restrict__ den,
    const int* __restrict__ ei, float* __restrict__ agg, int E){
  int t = blockIdx.x*256 + threadIdx.x;
  if (t >= E*20) return;
  int e = t/20, r = t - (t/20)*20;
  int d = ei[E + e];
  float attn = exb[e] / (den[d] + 1e-8f);
  float4 m4 = ((const float4*)(msgs + (size_t)e*80))[r];
  float* ap = agg + (size_t)d*80 + r*4;
  atomicAdd(ap+0, attn*m4.x);
  atomicAdd(ap+1, attn*m4.y);
  atomicAdd(ap+2, attn*m4.z);
  atomicAdd(ap+3, attn*m4.w);
}

__global__ void __launch_bounds__(256) k_node(const float* __restrict__ agg,
    const float* __restrict__ nf,
    const float* __restrict__ Wout_s, const float* __restrict__ Wout_v,
    const float* __restrict__ Wg_s, const float* __restrict__ Wg_v,
    float* __restrict__ xbuf, float* __restrict__ bnacc, int N)
{
  __shared__ float t1[4][96];
  __shared__ float t2[4][96];
  __shared__ float bnl[80];
  int t = threadIdx.x, l = t & 63, wv = t >> 6;
  int n = blockIdx.x*4 + wv;
  bool act = (n < N);
  int nc = act ? n : 0;
  if (t < 80) bnl[t] = 0.f;
  __syncthreads();
  const float* arow = agg + (size_t)nc*80;
  const float iS = 0.17677669529663687f;  // 1/sqrt(32)
  const float iV = 0.25f;                 // 1/sqrt(16)
  for (int o = l; o < 80; o += 64){
    float val = 0.f;
    if (o < 32){
      for (int s = 0; s < 32; ++s) val += arow[s]*Wout_s[s*32+o];
      val *= iS;
    } else {
      int w = (o-32)/3, c = (o-32)-w*3;
      for (int v = 0; v < 16; ++v) val += arow[32+v*3+c]*Wout_v[v*16+w];
      val *= iV;
    }
    t1[wv][o] = val;
  }
  __syncthreads();
  for (int o = l; o < 96; o += 64){
    float val = 0.f;
    if (o < 48){
      for (int k = 0; k < 32; ++k) val += t1[wv][k]*Wg_s[k*48+o];
      val *= iS;
    } else {
      int w = (o-48)/3, c = (o-48)-w*3;
      for (int v = 0; v < 16; ++v) val += t1[wv][32+v*3+c]*Wg_v[v*16+w];
      val *= iV;
    }
    t2[wv][o] = val;
  }
  __syncthreads();
  for (int o = l; o < 80; o += 64){
    float x;
    if (o < 32){
      x = silu_f(t2[wv][o]) + nf[(size_t)nc*80+o];
      if (act){
        xbuf[(size_t)n*80+o] = x;
        atomicAdd(&bnl[o], x);
        atomicAdd(&bnl[32+o], x*x);
      }
    } else {
      int w = (o-32)/3;
      x = sigm_f(t2[wv][32+w]) * t2[wv][48+(o-32)] + nf[(size_t)nc*80+o];
      if (act){
        xbuf[(size_t)n*80+o] = x;
        atomicAdd(&bnl[64+w], x*x);
      }
    }
  }
  __syncthreads();
  if (t < 80) atomicAdd(&bnacc[t], bnl[t]);
}

__global__ void k_bn(const float* __restrict__ bnacc,
    const float* __restrict__ bn_ws, const float* __restrict__ bn_bs,
    const float* __restrict__ bn_wv, float* __restrict__ coef, int N){
  int t = threadIdx.x;
  float fN = (float)N;
  if (t < 32){
    float mean = bnacc[t]/fN;
    float var = bnacc[32+t]/fN - mean*mean;
    float cm = bn_ws[t]*rsqrtf(var + 1e-5f);
    coef[t] = cm;
    coef[32+t] = bn_bs[t] - mean*cm;
  } else if (t < 48){
    int v = t - 32;
    float vn = bnacc[64+v]/(3.f*fN);
    coef[64+v] = bn_wv[v]*rsqrtf(vn + 1e-5f);
  }
}

__global__ void __launch_bounds__(256) k_out(const float* __restrict__ xbuf,
    const float* __restrict__ coef, float* __restrict__ out, int N){
  int t = blockIdx.x*256 + threadIdx.x;
  if (t >= N*80) return;
  int n = t/80, o = t - n*80;
  float x = xbuf[t];
  out[t] = (o < 32) ? (x*coef[o] + coef[32+o]) : (x*coef[64+(o-32)/3]);
}

extern "C" void kernel_launch(void* const* d_in, const int* in_sizes, int n_in,
                              void* d_out, int out_size, void* d_ws, size_t ws_size,
                              hipStream_t stream) {
  const float* nf     = (const float*)d_in[0];
  const int*   ei     = (const int*)  d_in[1];
  const float* sh     = (const float*)d_in[2];
  const float* radial = (const float*)d_in[3];
  const float* env    = (const float*)d_in[4];
  const float* W1     = (const float*)d_in[5];
  const float* b1     = (const float*)d_in[6];
  const float* W2     = (const float*)d_in[7];
  const float* b2     = (const float*)d_in[8];
  const float* Wq     = (const float*)d_in[9];
  const float* bq     = (const float*)d_in[10];
  const float* Wk     = (const float*)d_in[11];
  const float* bk     = (const float*)d_in[12];
  const float* Wout_s = (const float*)d_in[13];
  const float* Wout_v = (const float*)d_in[14];
  const float* Wg_s   = (const float*)d_in[15];
  const float* Wg_v   = (const float*)d_in[16];
  const float* bn_ws  = (const float*)d_in[17];
  const float* bn_bs  = (const float*)d_in[18];
  const float* bn_wv  = (const float*)d_in[19];

  const int E = in_sizes[4];
  const int N = in_sizes[0] / 80;

  float* ws = (float*)d_ws;
  size_t off = 0;
  __bf16* w2t  = (__bf16*)(ws + off); off += 81920;  // 2*2560*32 bf16
  float* msgs   = ws + off; off += (size_t)E*80;
  float* logits = ws + off; off += E;
  float* exb    = ws + off; off += E;
  unsigned* mx  = (unsigned*)(ws + off); off += N;
  float* den    = ws + off; off += N;
  float* agg    = ws + off; off += (size_t)N*80;
  float* xbuf   = ws + off; off += (size_t)N*80;
  float* bnacc  = ws + off; off += 80;
  float* coef   = ws + off; off += 80;

  k_prep<<<640, 256, 0, stream>>>(W2, w2t);
  k_init<<<(N*80 + 255)/256, 256, 0, stream>>>(mx, den, agg, bnacc, N);
  k_edge<<<(E + 15)/16, 256, 0, stream>>>(nf, ei, sh, radial, env,
      W1, b1, w2t, b2, Wq, bq, Wk, bk, msgs, logits, mx, E);
  k_soft1<<<(E + 255)/256, 256, 0, stream>>>(logits, ei, mx, den, exb, E);
  k_scatter<<<(E*20 + 255)/256, 256, 0, stream>>>(msgs, exb, den, ei, agg, E);
  k_node<<<(N + 3)/4, 256, 0, stream>>>(agg, nf, Wout_s, Wout_v, Wg_s, Wg_v, xbuf, bnacc, N);
  k_bn<<<1, 64, 0, stream>>>(bnacc, bn_ws, bn_bs, bn_wv, coef, N);
  k_out<<<(N*80 + 255)/256, 256, 0, stream>>>(xbuf, coef, (float*)d_out, N);
}

// Round 5
// 488.201 us; speedup vs baseline: 5.8843x; 1.3497x over previous
//
#include <hip/hip_runtime.h>
#include <math.h>

typedef __bf16 bf16x8 __attribute__((ext_vector_type(8)));
typedef float  f32x4  __attribute__((ext_vector_type(4)));

__device__ __forceinline__ float silu_f(float x){ return x / (1.f + __expf(-x)); }
__device__ __forceinline__ float sigm_f(float x){ return 1.f / (1.f + __expf(-x)); }

// W2 (fp32 [64][2560]) -> W2t (bf16, [kc][2560][32]), kc = h>>5, hp = h&31
__global__ void __launch_bounds__(256) k_prep(const float* __restrict__ W2, __bf16* __restrict__ W2t){
  int gid = blockIdx.x*256 + threadIdx.x;   // 163840 total
  int h = gid / 2560;
  int col = gid - h*2560;
  int kc = h >> 5, hp = h & 31;
  W2t[(size_t)kc*81920 + col*32 + hp] = (__bf16)W2[gid];
}

__global__ void __launch_bounds__(256) k_zero(int* cnt, float* bnacc, int N){
  int t = blockIdx.x*256 + threadIdx.x;
  if (t < N) cnt[t] = 0;
  if (t < 80) bnacc[t] = 0.f;
}

__global__ void __launch_bounds__(256) k_hist(const int* __restrict__ ei, int* __restrict__ cnt, int E){
  int e = blockIdx.x*256 + threadIdx.x;
  if (e < E) atomicAdd(&cnt[ei[E+e]], 1);
}

__global__ void __launch_bounds__(1024) k_scan(const int* __restrict__ cnt,
    int* __restrict__ rowp, int* __restrict__ cursor, int N, int E){
  __shared__ int part[1024];
  int t = threadIdx.x;
  int chunk = (N + 1023) >> 10;
  int lo = t*chunk, hi = min(lo+chunk, N);
  int s = 0;
  for (int i = lo; i < hi; ++i) s += cnt[i];
  part[t] = s;
  __syncthreads();
  for (int off = 1; off < 1024; off <<= 1){
    int v = (t >= off) ? part[t-off] : 0;
    __syncthreads();
    part[t] += v;
    __syncthreads();
  }
  int base = (t == 0) ? 0 : part[t-1];
  for (int i = lo; i < hi; ++i){
    rowp[i] = base; cursor[i] = base;
    base += cnt[i];
  }
  if (t == 1023) rowp[N] = E;
}

__global__ void __launch_bounds__(256) k_place(const int* __restrict__ ei,
    int* __restrict__ cursor, int* __restrict__ eord, int E){
  int e = blockIdx.x*256 + threadIdx.x;
  if (e >= E) return;
  int d = ei[E+e];
  int pos = atomicAdd(&cursor[d], 1);
  eord[pos] = e;
}

// 16 edges / 256-thread block, bf16 MFMA over the h-contraction.
// Bias b2 added directly to MFMA output before coefficient multiply.
// Coefficient layouts transposed ([r][e], pad 20) -> conflict-free b128 reads.
__global__ void __launch_bounds__(256) k_edge(
    const float* __restrict__ nf, const int* __restrict__ ei,
    const float* __restrict__ sh, const float* __restrict__ radial,
    const float* __restrict__ env,
    const float* __restrict__ W1, const float* __restrict__ b1,
    const __bf16* __restrict__ W2t, const float* __restrict__ b2,
    const float* __restrict__ Wq, const float* __restrict__ bq,
    const float* __restrict__ Wk, const float* __restrict__ bk,
    float* __restrict__ msgs, float* __restrict__ logits, int E)
{
  __shared__ __bf16 u_lds[16][72];
  __shared__ float featT[80][17];
  __shared__ float cABt[48][20];
  __shared__ float cVt[64][3][20];
  __shared__ float macc[16][84];
  __shared__ float shlT[4][17];
  __shared__ float radl[16][17];
  __shared__ float w1l[1024];
  __shared__ float b1l[64];
  __shared__ int   src_l[16], dst_l[16];

  const int t = threadIdx.x;
  const int e0 = blockIdx.x*16;

  // ---- stage 1: indices, sh, radial, W1, b1; zero macc
  if (t < 16){ int ec = min(e0+t, E-1); src_l[t] = ei[ec]; dst_l[t] = ei[E+ec]; }
  if (t >= 64 && t < 128){
    int i = t-64; int e = i>>2, c = i&3;
    int ec = min(e0+e, E-1);
    shlT[c][e] = sh[(size_t)ec*4+c];
  }
  if (t >= 128 && t < 192) b1l[t-128] = b1[t-128];
  {
    int e = t>>4, r = t&15;
    int ec = min(e0+e, E-1);
    radl[e][r] = radial[(size_t)ec*16+r];
  }
  *(float4*)&w1l[t*4] = ((const float4*)W1)[t];
  for (int i = t; i < 1344; i += 256) ((float*)macc)[i] = 0.f;
  __syncthreads();

  // ---- stage 2: featT (transposed) + u = silu(radial@W1+b1) -> bf16
  for (int i = t; i < 1280; i += 256){
    int e = i / 80, idx = i - e*80;
    featT[idx][e] = nf[(size_t)src_l[e]*80 + idx];
  }
  for (int i = t; i < 1024; i += 256){
    int e = i & 15, h = i >> 4;
    float acc = b1l[h];
    #pragma unroll
    for (int r = 0; r < 16; ++r) acc += radl[e][r]*w1l[r*64+h];
    u_lds[e][h] = (__bf16)silu_f(acc);
  }
  __syncthreads();

  const float inv_s3 = 0.57735026918962576f;
  const float inv_s2 = 0.70710678118654752f;
  const float a0 = 0.14433756729740643f;  // 1/sqrt(48)
  const float a1 = 0.125f;                // 1/sqrt(64)

  // ---- stage 3: coefficients (transposed layouts)
  for (int i = t; i < 768; i += 256){
    int r = i >> 4, e = i & 15;
    float val;
    if (r < 32) val = a0 * shlT[0][e] * featT[r][e];
    else {
      int v = r - 32;
      float dot = (featT[32+v*3][e]*shlT[1][e] + featT[33+v*3][e]*shlT[2][e]
                 + featT[34+v*3][e]*shlT[3][e]) * inv_s3;
      val = a0 * dot;
    }
    cABt[r][e] = val;
  }
  for (int i = t; i < 3072; i += 256){
    int e = i & 15, r = (i >> 4) & 63, c = i >> 10;
    float val;
    if (r < 32) val = a1 * shlT[1+c][e] * featT[r][e];
    else if (r < 48){
      int v = r - 32;
      val = a1 * shlT[0][e] * featT[32+v*3+c][e];
    } else {
      int v = r - 48;
      int c1 = c+1; if (c1 > 2) c1 -= 3;
      int c2 = c+2; if (c2 > 2) c2 -= 3;
      val = a1 * inv_s2 * (featT[32+v*3+c1][e]*shlT[1+c2][e]
                         - featT[32+v*3+c2][e]*shlT[1+c1][e]);
    }
    cVt[r][c][e] = val;
  }
  __syncthreads();

  // ---- stage 4: MFMA tile loop (40 col-tiles per wave)
  const int lane = t & 63;
  const int wv   = t >> 6;
  const int quad = lane >> 4;
  const int nlo  = lane & 15;

  bf16x8 afr0 = *(const bf16x8*)&u_lds[nlo][quad*8];
  bf16x8 afr1 = *(const bf16x8*)&u_lds[nlo][32 + quad*8];

  float accS0[4] = {0,0,0,0};
  float accS1[4] = {0,0,0,0};
  float accV0[4] = {0,0,0,0};
  float accV1[4] = {0,0,0,0};
  float accV2[4] = {0,0,0,0};

  for (int it = wv*40; it < wv*40 + 40; ++it){
    const int n0 = it*16;
    const __bf16* bp = W2t + (size_t)(n0 + nlo)*32 + quad*8;
    bf16x8 bf0 = *(const bf16x8*)(bp);
    bf16x8 bf1 = *(const bf16x8*)(bp + 81920);
    const float b2c = b2[n0 + nlo];
    f32x4 d = {0.f,0.f,0.f,0.f};
    d = __builtin_amdgcn_mfma_f32_16x16x32_bf16(afr0, bf0, d, 0, 0, 0);
    d = __builtin_amdgcn_mfma_f32_16x16x32_bf16(afr1, bf1, d, 0, 0, 0);
    if (it < 96){
      const int r = it >> 1;
      const float4 c4 = *(const float4*)&cABt[r][quad*4];
      if (it & 1){
        accS1[0] += c4.x*(d[0]+b2c); accS1[1] += c4.y*(d[1]+b2c);
        accS1[2] += c4.z*(d[2]+b2c); accS1[3] += c4.w*(d[3]+b2c);
      } else {
        accS0[0] += c4.x*(d[0]+b2c); accS0[1] += c4.y*(d[1]+b2c);
        accS0[2] += c4.z*(d[2]+b2c); accS0[3] += c4.w*(d[3]+b2c);
      }
    } else {
      const int r = it - 96;
      const float4 v0 = *(const float4*)&cVt[r][0][quad*4];
      const float4 v1 = *(const float4*)&cVt[r][1][quad*4];
      const float4 v2 = *(const float4*)&cVt[r][2][quad*4];
      const float d0 = d[0]+b2c, d1 = d[1]+b2c, d2 = d[2]+b2c, d3 = d[3]+b2c;
      accV0[0] += v0.x*d0; accV0[1] += v0.y*d1; accV0[2] += v0.z*d2; accV0[3] += v0.w*d3;
      accV1[0] += v1.x*d0; accV1[1] += v1.y*d1; accV1[2] += v1.z*d2; accV1[3] += v1.w*d3;
      accV2[0] += v2.x*d0; accV2[1] += v2.y*d1; accV2[2] += v2.z*d2; accV2[3] += v2.w*d3;
    }
  }

  // ---- cross-wave reduce into macc (stride 84 breaks bank aliasing)
  if (wv != 3){
    #pragma unroll
    for (int reg = 0; reg < 4; ++reg){
      const int m = quad*4+reg;
      atomicAdd(&macc[m][nlo],    accS0[reg]);
      atomicAdd(&macc[m][16+nlo], accS1[reg]);
    }
  }
  if (wv >= 2){
    #pragma unroll
    for (int reg = 0; reg < 4; ++reg){
      const int m = quad*4+reg;
      atomicAdd(&macc[m][32+nlo*3+0], accV0[reg]);
      atomicAdd(&macc[m][32+nlo*3+1], accV1[reg]);
      atomicAdd(&macc[m][32+nlo*3+2], accV2[reg]);
    }
  }
  __syncthreads();

  // ---- logits (waves 0-1: 8 edges each)
  if (t < 128){
    const int l = t & 63;
    const int e = (t >> 6)*8 + (l >> 3);
    const int kq = l & 7;
    const int eg = e0 + e;
    const bool act = (eg < E);
    float4 ms = *(const float4*)&macc[e][kq*4];
    int dn = dst_l[e];
    float4 qs = *(const float4*)(nf + (size_t)dn*80 + kq*4);
    float pk[8], pq[8];
    #pragma unroll
    for (int j = 0; j < 8; ++j){
      pk[j] = ms.x*Wk[(kq*4+0)*8+j] + ms.y*Wk[(kq*4+1)*8+j]
            + ms.z*Wk[(kq*4+2)*8+j] + ms.w*Wk[(kq*4+3)*8+j];
      pq[j] = qs.x*Wq[(kq*4+0)*8+j] + qs.y*Wq[(kq*4+1)*8+j]
            + qs.z*Wq[(kq*4+2)*8+j] + qs.w*Wq[(kq*4+3)*8+j];
    }
    #pragma unroll
    for (int m = 1; m < 8; m <<= 1){
      #pragma unroll
      for (int j = 0; j < 8; ++j){
        pk[j] += __shfl_xor(pk[j], m);
        pq[j] += __shfl_xor(pq[j], m);
      }
    }
    if (kq == 0 && act){
      float lg = 0.f;
      #pragma unroll
      for (int j = 0; j < 8; ++j) lg += (pq[j]+bq[j])*(pk[j]+bk[j]);
      lg *= 0.35355339059327373f;  // 1/sqrt(8)
      lg += logf(env[eg] + 1e-8f);
      logits[eg] = lg;
    }
  }

  // ---- store messages
  for (int i = t; i < 320; i += 256){
    int e = i/20, r = i - (i/20)*20;
    if (e0 + e < E)
      ((float4*)(msgs + (size_t)(e0+e)*80))[r] = *(const float4*)&macc[e][r*4];
  }
}

// One wave per node: softmax over its CSR edge list (shuffle reduce),
// gather attn*msgs coalesced, then fused node matmuls + gate + residual + BN stats.
__global__ void __launch_bounds__(256) k_agg(
    const float* __restrict__ msgs, const float* __restrict__ logits,
    const int* __restrict__ eord, const int* __restrict__ rowp,
    const float* __restrict__ nf,
    const float* __restrict__ Wout_s, const float* __restrict__ Wout_v,
    const float* __restrict__ Wg_s, const float* __restrict__ Wg_v,
    float* __restrict__ xbuf, float* __restrict__ bnacc, int N)
{
  __shared__ float aggl[4][80];
  __shared__ float t1[4][96];
  __shared__ float t2[4][96];
  __shared__ float bnl[80];
  const int t = threadIdx.x, l = t & 63, wv = t >> 6;
  const int n = blockIdx.x*4 + wv;
  const bool act = (n < N);
  const int nc = act ? n : (N-1);
  if (t < 80) bnl[t] = 0.f;

  const int r0 = rowp[nc], r1 = rowp[nc+1];
  const int deg = act ? (r1 - r0) : 0;

  // pass 1: max logit
  float mym = -3.4e38f;
  for (int i = l; i < deg; i += 64)
    mym = fmaxf(mym, logits[eord[r0+i]]);
  #pragma unroll
  for (int s = 32; s; s >>= 1) mym = fmaxf(mym, __shfl_xor(mym, s));
  // pass 2: denominator
  float myden = 0.f;
  for (int i = l; i < deg; i += 64)
    myden += __expf(logits[eord[r0+i]] - mym);
  #pragma unroll
  for (int s = 32; s; s >>= 1) myden += __shfl_xor(myden, s);
  const float inv = 1.f/(myden + 1e-8f);
  // pass 3: gather-accumulate (lanes = slots)
  float acc0 = 0.f, acc1 = 0.f;
  for (int c0 = 0; c0 < deg; c0 += 64){
    int len = min(64, deg - c0);
    int e = 0; float ex = 0.f;
    if (l < len){ e = eord[r0+c0+l]; ex = __expf(logits[e] - mym); }
    for (int j = 0; j < len; ++j){
      float a = __shfl(ex, j);
      int  ee = __shfl(e, j);
      const float* mrow = msgs + (size_t)ee*80;
      acc0 += a * mrow[l];
      if (l < 16) acc1 += a * mrow[64+l];
    }
  }
  aggl[wv][l] = acc0 * inv;
  if (l < 16) aggl[wv][64+l] = acc1 * inv;
  __syncthreads();

  // ---- fused node phase (original k_node)
  const float* arow = &aggl[wv][0];
  const float iS = 0.17677669529663687f;  // 1/sqrt(32)
  const float iV = 0.25f;                 // 1/sqrt(16)
  for (int o = l; o < 80; o += 64){
    float val = 0.f;
    if (o < 32){
      for (int s = 0; s < 32; ++s) val += arow[s]*Wout_s[s*32+o];
      val *= iS;
    } else {
      int w = (o-32)/3, c = (o-32)-w*3;
      for (int v = 0; v < 16; ++v) val += arow[32+v*3+c]*Wout_v[v*16+w];
      val *= iV;
    }
    t1[wv][o] = val;
  }
  __syncthreads();
  for (int o = l; o < 96; o += 64){
    float val = 0.f;
    if (o < 48){
      for (int k = 0; k < 32; ++k) val += t1[wv][k]*Wg_s[k*48+o];
      val *= iS;
    } else {
      int w = (o-48)/3, c = (o-48)-w*3;
      for (int v = 0; v < 16; ++v) val += t1[wv][32+v*3+c]*Wg_v[v*16+w];
      val *= iV;
    }
    t2[wv][o] = val;
  }
  __syncthreads();
  for (int o = l; o < 80; o += 64){
    float x;
    if (o < 32){
      x = silu_f(t2[wv][o]) + nf[(size_t)nc*80+o];
      if (act){
        xbuf[(size_t)n*80+o] = x;
        atomicAdd(&bnl[o], x);
        atomicAdd(&bnl[32+o], x*x);
      }
    } else {
      int w = (o-32)/3;
      x = sigm_f(t2[wv][32+w]) * t2[wv][48+(o-32)] + nf[(size_t)nc*80+o];
      if (act){
        xbuf[(size_t)n*80+o] = x;
        atomicAdd(&bnl[64+w], x*x);
      }
    }
  }
  __syncthreads();
  if (t < 80) atomicAdd(&bnacc[t], bnl[t]);
}

__global__ void k_bn(const float* __restrict__ bnacc,
    const float* __restrict__ bn_ws, const float* __restrict__ bn_bs,
    const float* __restrict__ bn_wv, float* __restrict__ coef, int N){
  int t = threadIdx.x;
  float fN = (float)N;
  if (t < 32){
    float mean = bnacc[t]/fN;
    float var = bnacc[32+t]/fN - mean*mean;
    float cm = bn_ws[t]*rsqrtf(var + 1e-5f);
    coef[t] = cm;
    coef[32+t] = bn_bs[t] - mean*cm;
  } else if (t < 48){
    int v = t - 32;
    float vn = bnacc[64+v]/(3.f*fN);
    coef[64+v] = bn_wv[v]*rsqrtf(vn + 1e-5f);
  }
}

__global__ void __launch_bounds__(256) k_out(const float* __restrict__ xbuf,
    const float* __restrict__ coef, float* __restrict__ out, int N){
  int t = blockIdx.x*256 + threadIdx.x;
  if (t >= N*80) return;
  int n = t/80, o = t - n*80;
  float x = xbuf[t];
  out[t] = (o < 32) ? (x*coef[o] + coef[32+o]) : (x*coef[64+(o-32)/3]);
}

extern "C" void kernel_launch(void* const* d_in, const int* in_sizes, int n_in,
                              void* d_out, int out_size, void* d_ws, size_t ws_size,
                              hipStream_t stream) {
  const float* nf     = (const float*)d_in[0];
  const int*   ei     = (const int*)  d_in[1];
  const float* sh     = (const float*)d_in[2];
  const float* radial = (const float*)d_in[3];
  const float* env    = (const float*)d_in[4];
  const float* W1     = (const float*)d_in[5];
  const float* b1     = (const float*)d_in[6];
  const float* W2     = (const float*)d_in[7];
  const float* b2     = (const float*)d_in[8];
  const float* Wq     = (const float*)d_in[9];
  const float* bq     = (const float*)d_in[10];
  const float* Wk     = (const float*)d_in[11];
  const float* bk     = (const float*)d_in[12];
  const float* Wout_s = (const float*)d_in[13];
  const float* Wout_v = (const float*)d_in[14];
  const float* Wg_s   = (const float*)d_in[15];
  const float* Wg_v   = (const float*)d_in[16];
  const float* bn_ws  = (const float*)d_in[17];
  const float* bn_bs  = (const float*)d_in[18];
  const float* bn_wv  = (const float*)d_in[19];

  const int E = in_sizes[4];
  const int N = in_sizes[0] / 80;

  float* ws = (float*)d_ws;
  size_t off = 0;
  __bf16* w2t   = (__bf16*)(ws + off); off += 81920;   // [2][2560][32] bf16
  float* msgs   = ws + off; off += (size_t)E*80;
  float* logits = ws + off; off += E;
  int* eord     = (int*)(ws + off); off += E;
  int* cnt      = (int*)(ws + off); off += N;
  int* rowp     = (int*)(ws + off); off += N+1;
  int* cursor   = (int*)(ws + off); off += N;
  float* xbuf   = ws + off; off += (size_t)N*80;
  float* bnacc  = ws + off; off += 80;
  float* coef   = ws + off; off += 80;

  k_prep<<<640, 256, 0, stream>>>(W2, w2t);
  k_zero<<<(N + 255)/256, 256, 0, stream>>>(cnt, bnacc, N);
  k_hist<<<(E + 255)/256, 256, 0, stream>>>(ei, cnt, E);
  k_scan<<<1, 1024, 0, stream>>>(cnt, rowp, cursor, N, E);
  k_edge<<<(E + 15)/16, 256, 0, stream>>>(nf, ei, sh, radial, env,
      W1, b1, w2t, b2, Wq, bq, Wk, bk, msgs, logits, E);
  k_place<<<(E + 255)/256, 256, 0, stream>>>(ei, cursor, eord, E);
  k_agg<<<(N + 3)/4, 256, 0, stream>>>(msgs, logits, eord, rowp, nf,
      Wout_s, Wout_v, Wg_s, Wg_v, xbuf, bnacc, N);
  k_bn<<<1, 64, 0, stream>>>(bnacc, bn_ws, bn_bs, bn_wv, coef, N);
  k_out<<<(N*80 + 255)/256, 256, 0, stream>>>(xbuf, coef, (float*)d_out, N);
}

// Round 6
// 434.629 us; speedup vs baseline: 6.6096x; 1.1233x over previous
//
#include <hip/hip_runtime.h>
#include <math.h>

typedef __bf16 bf16x8 __attribute__((ext_vector_type(8)));
typedef float  f32x4  __attribute__((ext_vector_type(4)));

__device__ __forceinline__ float silu_f(float x){ return x / (1.f + __expf(-x)); }
__device__ __forceinline__ float sigm_f(float x){ return 1.f / (1.f + __expf(-x)); }

// W2 (fp32 [64][2560]) -> W2t (bf16, [kc][2560][32]), kc = h>>5, hp = h&31
__global__ void __launch_bounds__(256) k_prep(const float* __restrict__ W2, __bf16* __restrict__ W2t){
  int gid = blockIdx.x*256 + threadIdx.x;   // 163840 total
  int h = gid / 2560;
  int col = gid - h*2560;
  int kc = h >> 5, hp = h & 31;
  W2t[(size_t)kc*81920 + col*32 + hp] = (__bf16)W2[gid];
}

__global__ void __launch_bounds__(256) k_zero(int* cnt, float* bnacc, int N){
  int t = blockIdx.x*256 + threadIdx.x;
  if (t < N) cnt[t] = 0;
  if (t < 80) bnacc[t] = 0.f;
}

__global__ void __launch_bounds__(256) k_hist(const int* __restrict__ ei, int* __restrict__ cnt, int E){
  int e = blockIdx.x*256 + threadIdx.x;
  if (e < E) atomicAdd(&cnt[ei[E+e]], 1);
}

__global__ void __launch_bounds__(1024) k_scan(const int* __restrict__ cnt,
    int* __restrict__ rowp, int* __restrict__ cursor, int N, int E){
  __shared__ int part[1024];
  int t = threadIdx.x;
  int chunk = (N + 1023) >> 10;
  int lo = t*chunk, hi = min(lo+chunk, N);
  int s = 0;
  for (int i = lo; i < hi; ++i) s += cnt[i];
  part[t] = s;
  __syncthreads();
  for (int off = 1; off < 1024; off <<= 1){
    int v = (t >= off) ? part[t-off] : 0;
    __syncthreads();
    part[t] += v;
    __syncthreads();
  }
  int base = (t == 0) ? 0 : part[t-1];
  for (int i = lo; i < hi; ++i){
    rowp[i] = base; cursor[i] = base;
    base += cnt[i];
  }
  if (t == 1023) rowp[N] = E;
}

__global__ void __launch_bounds__(256) k_place(const int* __restrict__ ei,
    int* __restrict__ cursor, int* __restrict__ perm, int E){
  int e = blockIdx.x*256 + threadIdx.x;
  if (e >= E) return;
  int d = ei[E+e];
  int pos = atomicAdd(&cursor[d], 1);
  perm[e] = pos;
}

// 16 edges / 256-thread block, bf16 MFMA over the h-contraction.
// Wave-specialized tile ranges (waves 0-1: scalar cols, 2-3: vector cols),
// 1-deep B prefetch, LDS unions for occupancy, CSR-ordered output.
__global__ void __launch_bounds__(256) k_edge(
    const float* __restrict__ nf, const int* __restrict__ ei,
    const float* __restrict__ sh, const float* __restrict__ radial,
    const float* __restrict__ env,
    const float* __restrict__ W1, const float* __restrict__ b1,
    const __bf16* __restrict__ W2t, const float* __restrict__ b2,
    const float* __restrict__ Wq, const float* __restrict__ bq,
    const float* __restrict__ Wk, const float* __restrict__ bk,
    const int* __restrict__ perm,
    float* __restrict__ msgs, float* __restrict__ logits_s, int E)
{
  __shared__ __bf16 u_lds[16][72];
  __shared__ float uniA[1360];          // featT[80][17] <-> macc[16][84]
  __shared__ float cABt[48][20];
  __shared__ float uniB[3840];          // w1l[1024] <-> cVt[64][3][20]
  __shared__ float shlT[4][17];
  __shared__ float radl[16][17];
  __shared__ float b1l[64];
  __shared__ int   src_l[16], dst_l[16], perm_l[16];

  float (*featT)[17] = (float(*)[17])uniA;
  float (*macc)[84]  = (float(*)[84])uniA;
  float* w1l = uniB;
  float (*cVt)[3][20] = (float(*)[3][20])uniB;

  const int t = threadIdx.x;
  const int e0 = blockIdx.x*16;

  // ---- stage 1: indices, sh, radial, W1, b1
  if (t < 16){ int ec = min(e0+t, E-1); src_l[t] = ei[ec]; dst_l[t] = ei[E+ec]; perm_l[t] = perm[ec]; }
  if (t >= 64 && t < 128){
    int i = t-64; int e = i>>2, c = i&3;
    int ec = min(e0+e, E-1);
    shlT[c][e] = sh[(size_t)ec*4+c];
  }
  if (t >= 128 && t < 192) b1l[t-128] = b1[t-128];
  {
    int e = t>>4, r = t&15;
    int ec = min(e0+e, E-1);
    radl[e][r] = radial[(size_t)ec*16+r];
  }
  *(float4*)&w1l[t*4] = ((const float4*)W1)[t];
  __syncthreads();

  // ---- stage 2: featT (transposed) + u = silu(radial@W1+b1) -> bf16
  for (int i = t; i < 1280; i += 256){
    int e = i / 80, idx = i - e*80;
    featT[idx][e] = nf[(size_t)src_l[e]*80 + idx];
  }
  for (int i = t; i < 1024; i += 256){
    int e = i & 15, h = i >> 4;
    float acc = b1l[h];
    #pragma unroll
    for (int r = 0; r < 16; ++r) acc += radl[e][r]*w1l[r*64+h];
    u_lds[e][h] = (__bf16)silu_f(acc);
  }
  __syncthreads();

  const float inv_s3 = 0.57735026918962576f;
  const float inv_s2 = 0.70710678118654752f;
  const float a0 = 0.14433756729740643f;  // 1/sqrt(48)
  const float a1 = 0.125f;                // 1/sqrt(64)

  // ---- stage 3: coefficients (transposed layouts); cVt overwrites w1l
  for (int i = t; i < 768; i += 256){
    int r = i >> 4, e = i & 15;
    float val;
    if (r < 32) val = a0 * shlT[0][e] * featT[r][e];
    else {
      int v = r - 32;
      float dot = (featT[32+v*3][e]*shlT[1][e] + featT[33+v*3][e]*shlT[2][e]
                 + featT[34+v*3][e]*shlT[3][e]) * inv_s3;
      val = a0 * dot;
    }
    cABt[r][e] = val;
  }
  // compute cVt into registers first (reads featT + w1l-free zone? no: reads featT, writes cVt which aliases w1l -- w1l dead after stage 2, safe)
  for (int i = t; i < 3072; i += 256){
    int e = i & 15, r = (i >> 4) & 63, c = i >> 10;
    float val;
    if (r < 32) val = a1 * shlT[1+c][e] * featT[r][e];
    else if (r < 48){
      int v = r - 32;
      val = a1 * shlT[0][e] * featT[32+v*3+c][e];
    } else {
      int v = r - 48;
      int c1 = c+1; if (c1 > 2) c1 -= 3;
      int c2 = c+2; if (c2 > 2) c2 -= 3;
      val = a1 * inv_s2 * (featT[32+v*3+c1][e]*shlT[1+c2][e]
                         - featT[32+v*3+c2][e]*shlT[1+c1][e]);
    }
    cVt[r][c][e] = val;
  }
  __syncthreads();

  // ---- zero macc (aliases featT, now dead)
  for (int i = t; i < 1344; i += 256) ((float*)macc)[i] = 0.f;
  __syncthreads();

  // ---- stage 4: MFMA tile loop, wave-specialized, 1-deep prefetch
  const int lane = t & 63;
  const int wv   = t >> 6;
  const int quad = lane >> 4;
  const int nlo  = lane & 15;

  bf16x8 afr0 = *(const bf16x8*)&u_lds[nlo][quad*8];
  bf16x8 afr1 = *(const bf16x8*)&u_lds[nlo][32 + quad*8];

  const bool scalarW = (wv < 2);
  const int itBeg = scalarW ? wv*48 : 96 + (wv-2)*32;
  const int itEnd = scalarW ? itBeg + 48 : itBeg + 32;

  float accS0[4] = {0,0,0,0};
  float accS1[4] = {0,0,0,0};
  float accV0[4] = {0,0,0,0};
  float accV1[4] = {0,0,0,0};
  float accV2[4] = {0,0,0,0};

  const __bf16* bpBase = W2t + (size_t)nlo*32 + quad*8;
  bf16x8 cb0 = *(const bf16x8*)(bpBase + (size_t)itBeg*512);
  bf16x8 cb1 = *(const bf16x8*)(bpBase + (size_t)itBeg*512 + 81920);
  float  cbc = b2[itBeg*16 + nlo];

  for (int it = itBeg; it < itEnd; ++it){
    bf16x8 nb0 = cb0, nb1 = cb1; float nbc = cbc;
    if (it + 1 < itEnd){
      const __bf16* bp = bpBase + (size_t)(it+1)*512;
      nb0 = *(const bf16x8*)(bp);
      nb1 = *(const bf16x8*)(bp + 81920);
      nbc = b2[(it+1)*16 + nlo];
    }
    f32x4 d = {0.f,0.f,0.f,0.f};
    d = __builtin_amdgcn_mfma_f32_16x16x32_bf16(afr0, cb0, d, 0, 0, 0);
    d = __builtin_amdgcn_mfma_f32_16x16x32_bf16(afr1, cb1, d, 0, 0, 0);
    if (scalarW){
      const int r = it >> 1;
      const float4 c4 = *(const float4*)&cABt[r][quad*4];
      if (it & 1){
        accS1[0] += c4.x*(d[0]+cbc); accS1[1] += c4.y*(d[1]+cbc);
        accS1[2] += c4.z*(d[2]+cbc); accS1[3] += c4.w*(d[3]+cbc);
      } else {
        accS0[0] += c4.x*(d[0]+cbc); accS0[1] += c4.y*(d[1]+cbc);
        accS0[2] += c4.z*(d[2]+cbc); accS0[3] += c4.w*(d[3]+cbc);
      }
    } else {
      const int r = it - 96;
      const float4 v0 = *(const float4*)&cVt[r][0][quad*4];
      const float4 v1 = *(const float4*)&cVt[r][1][quad*4];
      const float4 v2 = *(const float4*)&cVt[r][2][quad*4];
      const float d0 = d[0]+cbc, d1 = d[1]+cbc, d2 = d[2]+cbc, d3 = d[3]+cbc;
      accV0[0] += v0.x*d0; accV0[1] += v0.y*d1; accV0[2] += v0.z*d2; accV0[3] += v0.w*d3;
      accV1[0] += v1.x*d0; accV1[1] += v1.y*d1; accV1[2] += v1.z*d2; accV1[3] += v1.w*d3;
      accV2[0] += v2.x*d0; accV2[1] += v2.y*d1; accV2[2] += v2.z*d2; accV2[3] += v2.w*d3;
    }
    cb0 = nb0; cb1 = nb1; cbc = nbc;
  }

  // ---- cross-wave reduce into macc
  if (scalarW){
    #pragma unroll
    for (int reg = 0; reg < 4; ++reg){
      const int m = quad*4+reg;
      atomicAdd(&macc[m][nlo],    accS0[reg]);
      atomicAdd(&macc[m][16+nlo], accS1[reg]);
    }
  } else {
    #pragma unroll
    for (int reg = 0; reg < 4; ++reg){
      const int m = quad*4+reg;
      atomicAdd(&macc[m][32+nlo*3+0], accV0[reg]);
      atomicAdd(&macc[m][32+nlo*3+1], accV1[reg]);
      atomicAdd(&macc[m][32+nlo*3+2], accV2[reg]);
    }
  }
  __syncthreads();

  // ---- logits (waves 0-1: 8 edges each)
  if (t < 128){
    const int l = t & 63;
    const int e = (t >> 6)*8 + (l >> 3);
    const int kq = l & 7;
    const int eg = e0 + e;
    const bool act = (eg < E);
    float4 ms = *(const float4*)&macc[e][kq*4];
    int dn = dst_l[e];
    float4 qs = *(const float4*)(nf + (size_t)dn*80 + kq*4);
    float pk[8], pq[8];
    #pragma unroll
    for (int j = 0; j < 8; ++j){
      pk[j] = ms.x*Wk[(kq*4+0)*8+j] + ms.y*Wk[(kq*4+1)*8+j]
            + ms.z*Wk[(kq*4+2)*8+j] + ms.w*Wk[(kq*4+3)*8+j];
      pq[j] = qs.x*Wq[(kq*4+0)*8+j] + qs.y*Wq[(kq*4+1)*8+j]
            + qs.z*Wq[(kq*4+2)*8+j] + qs.w*Wq[(kq*4+3)*8+j];
    }
    #pragma unroll
    for (int m = 1; m < 8; m <<= 1){
      #pragma unroll
      for (int j = 0; j < 8; ++j){
        pk[j] += __shfl_xor(pk[j], m);
        pq[j] += __shfl_xor(pq[j], m);
      }
    }
    if (kq == 0 && act){
      float lg = 0.f;
      #pragma unroll
      for (int j = 0; j < 8; ++j) lg += (pq[j]+bq[j])*(pk[j]+bk[j]);
      lg *= 0.35355339059327373f;  // 1/sqrt(8)
      lg += logf(env[eg] + 1e-8f);
      logits_s[perm_l[e]] = lg;
    }
  }

  // ---- store messages in CSR order
  for (int i = t; i < 320; i += 256){
    int e = i/20, r = i - (i/20)*20;
    if (e0 + e < E)
      ((float4*)(msgs + (size_t)perm_l[e]*80))[r] = *(const float4*)&macc[e][r*4];
  }
}

// One wave per node: softmax over its CONTIGUOUS CSR range, coalesced
// 4-edge-unrolled gather, then fused node matmuls + gate + residual + BN stats.
__global__ void __launch_bounds__(256) k_agg(
    const float* __restrict__ msgs, const float* __restrict__ logits_s,
    const int* __restrict__ rowp, const float* __restrict__ nf,
    const float* __restrict__ Wout_s, const float* __restrict__ Wout_v,
    const float* __restrict__ Wg_s, const float* __restrict__ Wg_v,
    float* __restrict__ xbuf, float* __restrict__ bnacc, int N)
{
  __shared__ float aggl[4][80];
  __shared__ float t1[4][96];
  __shared__ float t2[4][96];
  __shared__ float bnl[80];
  const int t = threadIdx.x, l = t & 63, wv = t >> 6;
  const int n = blockIdx.x*4 + wv;
  const bool act = (n < N);
  const int nc = act ? n : (N-1);
  if (t < 80) bnl[t] = 0.f;

  const int r0 = rowp[nc], r1 = rowp[nc+1];
  const int deg = act ? (r1 - r0) : 0;

  // pass 1: max logit (contiguous)
  float mym = -3.4e38f;
  for (int i = l; i < deg; i += 64) mym = fmaxf(mym, logits_s[r0+i]);
  #pragma unroll
  for (int s = 32; s; s >>= 1) mym = fmaxf(mym, __shfl_xor(mym, s));
  // pass 2: denominator
  float myden = 0.f;
  for (int i = l; i < deg; i += 64) myden += __expf(logits_s[r0+i] - mym);
  #pragma unroll
  for (int s = 32; s; s >>= 1) myden += __shfl_xor(myden, s);
  const float inv = 1.f/(myden + 1e-8f);
  // pass 3: coalesced gather, 4 rows in flight
  float acc0 = 0.f, acc1 = 0.f;
  for (int c0 = 0; c0 < deg; c0 += 64){
    const int len = min(64, deg - c0);
    float ex = 0.f;
    if (l < len) ex = __expf(logits_s[r0+c0+l] - mym);
    for (int j0 = 0; j0 < len; j0 += 4){
      const int jn = len - j0;
      const float* base = msgs + (size_t)(r0+c0+j0)*80;
      float v0=0,v1=0,v2=0,v3=0, w0=0,w1=0,w2=0,w3=0;
      float a0_=0,a1_=0,a2_=0,a3_=0;
      v0 = base[l]; if (l < 16) w0 = base[64+l]; a0_ = __shfl(ex, j0);
      if (jn > 1){ v1 = base[80+l];  if (l < 16) w1 = base[144+l]; a1_ = __shfl(ex, j0+1); }
      if (jn > 2){ v2 = base[160+l]; if (l < 16) w2 = base[224+l]; a2_ = __shfl(ex, j0+2); }
      if (jn > 3){ v3 = base[240+l]; if (l < 16) w3 = base[304+l]; a3_ = __shfl(ex, j0+3); }
      acc0 += a0_*v0 + a1_*v1 + a2_*v2 + a3_*v3;
      if (l < 16) acc1 += a0_*w0 + a1_*w1 + a2_*w2 + a3_*w3;
    }
  }
  aggl[wv][l] = acc0 * inv;
  if (l < 16) aggl[wv][64+l] = acc1 * inv;
  __syncthreads();

  // ---- fused node phase
  const float* arow = &aggl[wv][0];
  const float iS = 0.17677669529663687f;  // 1/sqrt(32)
  const float iV = 0.25f;                 // 1/sqrt(16)
  for (int o = l; o < 80; o += 64){
    float val = 0.f;
    if (o < 32){
      for (int s = 0; s < 32; ++s) val += arow[s]*Wout_s[s*32+o];
      val *= iS;
    } else {
      int w = (o-32)/3, c = (o-32)-w*3;
      for (int v = 0; v < 16; ++v) val += arow[32+v*3+c]*Wout_v[v*16+w];
      val *= iV;
    }
    t1[wv][o] = val;
  }
  __syncthreads();
  for (int o = l; o < 96; o += 64){
    float val = 0.f;
    if (o < 48){
      for (int k = 0; k < 32; ++k) val += t1[wv][k]*Wg_s[k*48+o];
      val *= iS;
    } else {
      int w = (o-48)/3, c = (o-48)-w*3;
      for (int v = 0; v < 16; ++v) val += t1[wv][32+v*3+c]*Wg_v[v*16+w];
      val *= iV;
    }
    t2[wv][o] = val;
  }
  __syncthreads();
  for (int o = l; o < 80; o += 64){
    float x;
    if (o < 32){
      x = silu_f(t2[wv][o]) + nf[(size_t)nc*80+o];
      if (act){
        xbuf[(size_t)n*80+o] = x;
        atomicAdd(&bnl[o], x);
        atomicAdd(&bnl[32+o], x*x);
      }
    } else {
      int w = (o-32)/3;
      x = sigm_f(t2[wv][32+w]) * t2[wv][48+(o-32)] + nf[(size_t)nc*80+o];
      if (act){
        xbuf[(size_t)n*80+o] = x;
        atomicAdd(&bnl[64+w], x*x);
      }
    }
  }
  __syncthreads();
  if (t < 80) atomicAdd(&bnacc[t], bnl[t]);
}

__global__ void k_bn(const float* __restrict__ bnacc,
    const float* __restrict__ bn_ws, const float* __restrict__ bn_bs,
    const float* __restrict__ bn_wv, float* __restrict__ coef, int N){
  int t = threadIdx.x;
  float fN = (float)N;
  if (t < 32){
    float mean = bnacc[t]/fN;
    float var = bnacc[32+t]/fN - mean*mean;
    float cm = bn_ws[t]*rsqrtf(var + 1e-5f);
    coef[t] = cm;
    coef[32+t] = bn_bs[t] - mean*cm;
  } else if (t < 48){
    int v = t - 32;
    float vn = bnacc[64+v]/(3.f*fN);
    coef[64+v] = bn_wv[v]*rsqrtf(vn + 1e-5f);
  }
}

__global__ void __launch_bounds__(256) k_out(const float* __restrict__ xbuf,
    const float* __restrict__ coef, float* __restrict__ out, int N){
  int t = blockIdx.x*256 + threadIdx.x;
  if (t >= N*80) return;
  int n = t/80, o = t - n*80;
  float x = xbuf[t];
  out[t] = (o < 32) ? (x*coef[o] + coef[32+o]) : (x*coef[64+(o-32)/3]);
}

extern "C" void kernel_launch(void* const* d_in, const int* in_sizes, int n_in,
                              void* d_out, int out_size, void* d_ws, size_t ws_size,
                              hipStream_t stream) {
  const float* nf     = (const float*)d_in[0];
  const int*   ei     = (const int*)  d_in[1];
  const float* sh     = (const float*)d_in[2];
  const float* radial = (const float*)d_in[3];
  const float* env    = (const float*)d_in[4];
  const float* W1     = (const float*)d_in[5];
  const float* b1     = (const float*)d_in[6];
  const float* W2     = (const float*)d_in[7];
  const float* b2     = (const float*)d_in[8];
  const float* Wq     = (const float*)d_in[9];
  const float* bq     = (const float*)d_in[10];
  const float* Wk     = (const float*)d_in[11];
  const float* bk     = (const float*)d_in[12];
  const float* Wout_s = (const float*)d_in[13];
  const float* Wout_v = (const float*)d_in[14];
  const float* Wg_s   = (const float*)d_in[15];
  const float* Wg_v   = (const float*)d_in[16];
  const float* bn_ws  = (const float*)d_in[17];
  const float* bn_bs  = (const float*)d_in[18];
  const float* bn_wv  = (const float*)d_in[19];

  const int E = in_sizes[4];
  const int N = in_sizes[0] / 80;

  float* ws = (float*)d_ws;
  size_t off = 0;
  __bf16* w2t    = (__bf16*)(ws + off); off += 81920;   // [2][2560][32] bf16
  float* msgs    = ws + off; off += (size_t)E*80;
  float* logits_s= ws + off; off += E;
  int* perm      = (int*)(ws + off); off += E;
  int* cnt       = (int*)(ws + off); off += N;
  int* rowp      = (int*)(ws + off); off += N+1;
  int* cursor    = (int*)(ws + off); off += N;
  float* xbuf    = ws + off; off += (size_t)N*80;
  float* bnacc   = ws + off; off += 80;
  float* coef    = ws + off; off += 80;

  k_prep<<<640, 256, 0, stream>>>(W2, w2t);
  k_zero<<<(N + 255)/256, 256, 0, stream>>>(cnt, bnacc, N);
  k_hist<<<(E + 255)/256, 256, 0, stream>>>(ei, cnt, E);
  k_scan<<<1, 1024, 0, stream>>>(cnt, rowp, cursor, N, E);
  k_place<<<(E + 255)/256, 256, 0, stream>>>(ei, cursor, perm, E);
  k_edge<<<(E + 15)/16, 256, 0, stream>>>(nf, ei, sh, radial, env,
      W1, b1, w2t, b2, Wq, bq, Wk, bk, perm, msgs, logits_s, E);
  k_agg<<<(N + 3)/4, 256, 0, stream>>>(msgs, logits_s, rowp, nf,
      Wout_s, Wout_v, Wg_s, Wg_v, xbuf, bnacc, N);
  k_bn<<<1, 64, 0, stream>>>(bnacc, bn_ws, bn_bs, bn_wv, coef, N);
  k_out<<<(N*80 + 255)/256, 256, 0, stream>>>(xbuf, coef, (float*)d_out, N);
}